// Round 1
// baseline (253.941 us; speedup 1.0000x reference)
//
#include <hip/hip_runtime.h>
#include <hip/hip_bf16.h>
#include <math.h>

// ---------------------------------------------------------------------------
// MultiHeadAttention: B=4, S=2048, D=1024, H=16, Dh=64, causal. fp32 I/O.
// R9: attn re-tiled for occupancy. 32 q-tiles of 64 rows, paired (t, 31-t)
//     -> grid 1024 (was 512), uniform 33 k-iters/block, 4 waves x 16 rows.
//     Ks/Vs/Ps: unpadded 64-wide XOR-swizzled (GEMM-style) -> conflict-free
//     16B-aligned b128 reads + async global_load_lds K/V staging.
//     XCD-grouped block remap: each XCD owns 8 (b,h) streams (~4MB = its L2).
//     GEMMs unchanged from R8.
// Scratch: ws[0:16M)=q/ctx, [16:32M)=k, [32:48M)=vT, [48:50M)=woT;
//   d_out 32MB fp32 buffer holds xb(16M)+wcatT(6M), consumed pre-final-GEMM.
// ---------------------------------------------------------------------------

typedef __attribute__((ext_vector_type(8))) short short8;   // 8 bf16 = 4 VGPRs
typedef __attribute__((ext_vector_type(4))) float f32x4;

#define MFMA_BF16(a, b, c) __builtin_amdgcn_mfma_f32_16x16x32_bf16((a), (b), (c), 0, 0, 0)

__device__ __forceinline__ void gld_lds16(const void* g, void* l) {
  __builtin_amdgcn_global_load_lds((const __attribute__((address_space(1))) void*)g,
                                   (__attribute__((address_space(3))) void*)l, 16, 0, 0);
}

// ------------- merged prep: cast x -> bf16  +  transpose 4 weights ----------
// grid x: [0,8192) cast blocks; [8192, 8192+4096) transpose blocks.
__global__ void prep_kernel(const float* __restrict__ x, __hip_bfloat16* __restrict__ xb,
                            const float* __restrict__ W0, const float* __restrict__ W1,
                            const float* __restrict__ W2, const float* __restrict__ W3,
                            __hip_bfloat16* __restrict__ T0, __hip_bfloat16* __restrict__ T1,
                            __hip_bfloat16* __restrict__ T2, __hip_bfloat16* __restrict__ T3) {
  const int bid = blockIdx.x, tid = threadIdx.x;
  if (bid < 8192) {  // cast: 8192 blocks x 256 threads x 1 float4
    int i = bid * 256 + tid;
    float4 v = ((const float4*)x)[i];
    __align__(8) __hip_bfloat16 tmp[4] = {__float2bfloat16(v.x), __float2bfloat16(v.y),
                                          __float2bfloat16(v.z), __float2bfloat16(v.w)};
    ((ushort4*)xb)[i] = *(const ushort4*)tmp;
  } else {           // transpose: 4096 blocks (4 weights x 32 x 32 tiles)
    int zz = bid - 8192;
    int z = zz >> 10, rem = zz & 1023;
    const float* W = (z == 0) ? W0 : (z == 1) ? W1 : (z == 2) ? W2 : W3;
    __hip_bfloat16* Wt = (z == 0) ? T0 : (z == 1) ? T1 : (z == 2) ? T2 : T3;
    __shared__ float tile[32][33];
    int tx = tid & 31, ty = tid >> 5;                // (32,8)
    int n0 = (rem & 31) * 32, k0 = (rem >> 5) * 32;
#pragma unroll
    for (int i = 0; i < 4; ++i)
      tile[ty + i * 8][tx] = W[(size_t)(k0 + ty + i * 8) * 1024 + n0 + tx];
    __syncthreads();
#pragma unroll
    for (int i = 0; i < 4; ++i)
      Wt[(size_t)(n0 + ty + i * 8) * 1024 + k0 + tx] = __float2bfloat16(tile[tx][ty + i * 8]);
  }
}

// ------------- fused QKV GEMM over wcatT[3072][1024]; V written transposed ---
// grid (24, 64): part = x>>3 (0=q,1=k,2=v). 128x128 tiles, BK=64, K=1024.
// LDS: [128 rows][8 chunks of 16B], chunk XOR-swizzled by row&7.
// Q output pre-scaled by CSCL = (1/sqrt(64))*log2(e).
__global__ __launch_bounds__(256, 2) void gemm_qkv(
    const __hip_bfloat16* __restrict__ A, const __hip_bfloat16* __restrict__ Bt,
    __hip_bfloat16* __restrict__ q, __hip_bfloat16* __restrict__ k,
    __hip_bfloat16* __restrict__ vT) {
  __shared__ __align__(16) __hip_bfloat16 As[128 * 64];
  __shared__ __align__(16) __hip_bfloat16 Bs[128 * 64];
  const int tid = threadIdx.x;
  const int lane = tid & 63, wid = tid >> 6;
  const int quad = lane >> 4, l16 = lane & 15;
  const int part = blockIdx.x >> 3;
  const int n0 = (blockIdx.x & 7) * 128;
  const int gn0 = part * 1024 + n0;
  const int m0 = blockIdx.y * 128;
  const int wm = (wid & 1) * 64, wn = (wid >> 1) * 64;
  const int swz = l16 & 7;                    // row&7 for all fragment rows

  f32x4 acc[4][4] = {};

  for (int k0 = 0; k0 < 1024; k0 += 64) {
    __syncthreads();
#pragma unroll
    for (int i = 0; i < 4; ++i) {
      int sbase = __builtin_amdgcn_readfirstlane(wid * 256 + i * 64);
      int s = sbase + lane;                   // slot: row = s>>3, ch_phys = s&7
      int row = s >> 3;
      int ch = (s & 7) ^ (row & 7);           // logical chunk this slot holds
      gld_lds16(A + (size_t)(m0 + row) * 1024 + k0 + ch * 8, &As[sbase * 8]);
      gld_lds16(Bt + (size_t)(gn0 + row) * 1024 + k0 + ch * 8, &Bs[sbase * 8]);
    }
    __syncthreads();

    short8 af[4][2], bfr[4][2];
#pragma unroll
    for (int t = 0; t < 4; ++t)
#pragma unroll
      for (int kc = 0; kc < 2; ++kc) {
        int chp = (kc * 4 + quad) ^ swz;      // swizzled chunk
        af[t][kc]  = *(const short8*)&As[(wm + t * 16 + l16) * 64 + chp * 8];
        bfr[t][kc] = *(const short8*)&Bs[(wn + t * 16 + l16) * 64 + chp * 8];
      }
#pragma unroll
    for (int kc = 0; kc < 2; ++kc)
#pragma unroll
      for (int mt = 0; mt < 4; ++mt)
#pragma unroll
        for (int nt = 0; nt < 4; ++nt)
          acc[mt][nt] = MFMA_BF16(af[mt][kc], bfr[nt][kc], acc[mt][nt]);
  }

  const float CSCL = 0.18033688011112042f;  // (1/sqrt(64)) * log2(e)
  if (part < 2) {
    __hip_bfloat16* C = (part == 0) ? q : k;
    const float scl = (part == 0) ? CSCL : 1.0f;
#pragma unroll
    for (int mt = 0; mt < 4; ++mt)
#pragma unroll
      for (int nt = 0; nt < 4; ++nt) {
        int row = m0 + wm + mt * 16 + quad * 4;
        int col = n0 + wn + nt * 16 + l16;
#pragma unroll
        for (int r = 0; r < 4; ++r)
          C[(size_t)(row + r) * 1024 + col] = __float2bfloat16(acc[mt][nt][r] * scl);
      }
  } else {
#pragma unroll
    for (int mt = 0; mt < 4; ++mt)
#pragma unroll
      for (int nt = 0; nt < 4; ++nt) {
        int row = m0 + wm + mt * 16 + quad * 4;
        int nn = n0 + wn + nt * 16 + l16;
        __align__(8) __hip_bfloat16 p4[4];
#pragma unroll
        for (int r = 0; r < 4; ++r) p4[r] = __float2bfloat16(acc[mt][nt][r]);
        *(ushort4*)(vT + (size_t)nn * 8192 + row) = *(const ushort4*)p4;
      }
  }
}

// --------------- GEMM: C = A*Bt^T, fp32 out + bias; BK=64 swizzled ---------
__global__ __launch_bounds__(256, 2) void gemm_bt_f32out(
    const __hip_bfloat16* __restrict__ A, const __hip_bfloat16* __restrict__ Bt,
    float* __restrict__ C, const float* __restrict__ bias, int M, int N, int K) {
  __shared__ __align__(16) __hip_bfloat16 As[128 * 64];
  __shared__ __align__(16) __hip_bfloat16 Bs[128 * 64];
  const int tid = threadIdx.x;
  const int lane = tid & 63, wid = tid >> 6;
  const int quad = lane >> 4, l16 = lane & 15;
  const int m0 = blockIdx.y * 128, n0 = blockIdx.x * 128;
  const int wm = (wid & 1) * 64, wn = (wid >> 1) * 64;
  const int swz = l16 & 7;

  f32x4 acc[4][4] = {};

  for (int k0 = 0; k0 < K; k0 += 64) {
    __syncthreads();
#pragma unroll
    for (int i = 0; i < 4; ++i) {
      int sbase = __builtin_amdgcn_readfirstlane(wid * 256 + i * 64);
      int s = sbase + lane;
      int row = s >> 3;
      int ch = (s & 7) ^ (row & 7);
      gld_lds16(A + (size_t)(m0 + row) * K + k0 + ch * 8, &As[sbase * 8]);
      gld_lds16(Bt + (size_t)(n0 + row) * K + k0 + ch * 8, &Bs[sbase * 8]);
    }
    __syncthreads();

    short8 af[4][2], bfr[4][2];
#pragma unroll
    for (int t = 0; t < 4; ++t)
#pragma unroll
      for (int kc = 0; kc < 2; ++kc) {
        int chp = (kc * 4 + quad) ^ swz;
        af[t][kc]  = *(const short8*)&As[(wm + t * 16 + l16) * 64 + chp * 8];
        bfr[t][kc] = *(const short8*)&Bs[(wn + t * 16 + l16) * 64 + chp * 8];
      }
#pragma unroll
    for (int kc = 0; kc < 2; ++kc)
#pragma unroll
      for (int mt = 0; mt < 4; ++mt)
#pragma unroll
        for (int nt = 0; nt < 4; ++nt)
          acc[mt][nt] = MFMA_BF16(af[mt][kc], bfr[nt][kc], acc[mt][nt]);
  }

#pragma unroll
  for (int mt = 0; mt < 4; ++mt)
#pragma unroll
    for (int nt = 0; nt < 4; ++nt) {
      int row = m0 + wm + mt * 16 + quad * 4;
      int col = n0 + wn + nt * 16 + l16;
      float b = bias[col];
#pragma unroll
      for (int r = 0; r < 4; ++r)
        C[(size_t)(row + r) * N + col] = acc[mt][nt][r] + b;
    }
}

// ----------------------------- flash attention ------------------------------
// R9: 32 q-tiles of 64 rows per (b,h), paired (t, 31-t) -> uniform 33 k-iters.
// grid 1024 = 8 xcd * (8 (b,h)-groups * 16 pairs); 4 waves x 16 q-rows each.
// K/V staged via async global_load_lds into XOR-swizzled [64][8x16B] tiles
// (conflict-free, 16B-aligned b128 reads); per-wave P also swizzled.
// Max-free softmax (Q pre-scaled by 1/sqrt(64)*log2e in gemm_qkv).
__global__ __launch_bounds__(256, 4) void attn_kernel(
    const __hip_bfloat16* __restrict__ Q, const __hip_bfloat16* __restrict__ Km,
    const __hip_bfloat16* __restrict__ vT, __hip_bfloat16* __restrict__ ctx) {
  const int bid = blockIdx.x;
  // XCD-grouped remap (xcd = bid%8 heuristic): each XCD owns 8 full (b,h)
  // streams (8 * 512KB K+V ~= its 4MB L2), all 16 pair-blocks of a stream
  // co-located for L2 reuse of the doubled K/V re-reads.
  const int xcd = bid & 7, loc = bid >> 3;
  const int grp = xcd * 8 + (loc >> 4);     // b*16 + h
  const int p = loc & 15;                   // pair index
  const int h = grp & 15, b = grp >> 4;
  const size_t rbase = (size_t)b * 2048;
  const int tid = threadIdx.x, lane = tid & 63, wid = tid >> 6;
  const int quad = lane >> 4, l16 = lane & 15;
  const int sw = l16 & 7;                   // fragment-row swizzle (row&7)

  __shared__ __align__(16) __hip_bfloat16 Ks[64 * 64];      // [kpos][ch^row&7]
  __shared__ __align__(16) __hip_bfloat16 Vs[64 * 64];      // [d][ch^row&7]
  __shared__ __align__(16) __hip_bfloat16 Ps[4][16 * 64];   // per-wave P, swz

  const float NEG_BIG = -1e30f;             // exp2 -> exactly 0

#pragma unroll 1
  for (int sub = 0; sub < 2; ++sub) {
    const int t = sub ? (31 - p) : p;       // 64-row q-tile index
    const int q0 = t * 64;

    short8 qf[2];
#pragma unroll
    for (int kc = 0; kc < 2; ++kc)
      qf[kc] = *(const short8*)(Q + (rbase + q0 + wid * 16 + l16) * 1024 +
                                h * 64 + kc * 32 + quad * 8);

    f32x4 o[4] = {};
    f32x4 lp = {};                          // per-lane partial row sums

#pragma unroll 1
    for (int kt = 0; kt <= t; ++kt) {
      const int kbase = kt * 64;
      __syncthreads();  // previous tile's LDS reads done
      // stage K tile [kpos][d] and V tile [d][kpos] async, swizzled source:
      // LDS dest is linear (slot s = i*256 + wid*64 + lane), global chunk
      // pre-XORed so swizzled reads see logical data.
#pragma unroll
      for (int i = 0; i < 2; ++i) {
        int sbase = __builtin_amdgcn_readfirstlane(i * 256 + wid * 64);
        int s = sbase + lane;
        int row = s >> 3;
        int lch = (s & 7) ^ (row & 7);
        gld_lds16(Km + (rbase + kbase + row) * 1024 + h * 64 + lch * 8, &Ks[sbase * 8]);
        gld_lds16(vT + (size_t)(h * 64 + row) * 8192 + rbase + kbase + lch * 8,
                  &Vs[sbase * 8]);
      }
      __syncthreads();  // compiler drains vmcnt before barrier

      // QK^T: s[nt] = Q(16 rows) * K(4x16 kpos)
      f32x4 sv[4];
#pragma unroll
      for (int nt = 0; nt < 4; ++nt) {
        short8 k0 = *(const short8*)&Ks[(nt * 16 + l16) * 64 + ((quad ^ sw) << 3)];
        short8 k1 = *(const short8*)&Ks[(nt * 16 + l16) * 64 + (((4 + quad) ^ sw) << 3)];
        f32x4 z = {0.f, 0.f, 0.f, 0.f};
        z = MFMA_BF16(qf[0], k0, z);
        z = MFMA_BF16(qf[1], k1, z);
        sv[nt] = z;
      }
      if (kt == t) {  // diagonal tile: causal mask (kbase == q0)
#pragma unroll
        for (int nt = 0; nt < 4; ++nt)
#pragma unroll
          for (int r = 0; r < 4; ++r)
            if (nt * 16 + l16 > wid * 16 + quad * 4 + r) sv[nt][r] = NEG_BIG;
      }
      // max-free softmax: p = exp2(s); store P swizzled (per-wave, in-order
      // DS pipe -> no barrier needed before same-wave reads)
#pragma unroll
      for (int nt = 0; nt < 4; ++nt)
#pragma unroll
        for (int r = 0; r < 4; ++r) {
          float pv = __builtin_amdgcn_exp2f(sv[nt][r]);
          lp[r] += pv;
          int rrow = quad * 4 + r;
          int cph = (nt * 2 + (l16 >> 3)) ^ (rrow & 7);
          Ps[wid][rrow * 64 + cph * 8 + (l16 & 7)] = __float2bfloat16(pv);
        }
      // PV: A = P (A-frag), B = V (B-frag), both swizzled reads
      short8 pa0 = *(const short8*)&Ps[wid][l16 * 64 + ((quad ^ sw) << 3)];
      short8 pa1 = *(const short8*)&Ps[wid][l16 * 64 + (((4 + quad) ^ sw) << 3)];
#pragma unroll
      for (int dt = 0; dt < 4; ++dt) {
        short8 v0 = *(const short8*)&Vs[(dt * 16 + l16) * 64 + ((quad ^ sw) << 3)];
        short8 v1 = *(const short8*)&Vs[(dt * 16 + l16) * 64 + (((4 + quad) ^ sw) << 3)];
        o[dt] = MFMA_BF16(pa0, v0, o[dt]);
        o[dt] = MFMA_BF16(pa1, v1, o[dt]);
      }
    }

    // reduce l across the 16 lanes holding each row's columns, write ctx
#pragma unroll
    for (int msk = 1; msk <= 8; msk <<= 1)
#pragma unroll
      for (int r = 0; r < 4; ++r)
        lp[r] += __shfl_xor(lp[r], msk, 64);
    float inv[4];
#pragma unroll
    for (int r = 0; r < 4; ++r) inv[r] = 1.f / lp[r];
#pragma unroll
    for (int dt = 0; dt < 4; ++dt)
#pragma unroll
      for (int r = 0; r < 4; ++r)
        ctx[(rbase + q0 + wid * 16 + quad * 4 + r) * 1024 + h * 64 + dt * 16 + l16] =
            __float2bfloat16(o[dt][r] * inv[r]);
  }
}

// ------------------------------- launcher ----------------------------------
extern "C" void kernel_launch(void* const* d_in, const int* in_sizes, int n_in,
                              void* d_out, int out_size, void* d_ws, size_t ws_size,
                              hipStream_t stream) {
  const float* x  = (const float*)d_in[0];
  const float* Wq = (const float*)d_in[1];
  const float* Wk = (const float*)d_in[2];
  const float* Wv = (const float*)d_in[3];
  const float* Wo = (const float*)d_in[4];
  const float* bo = (const float*)d_in[5];
  float* out = (float*)d_out;

  char* ws = (char*)d_ws;
  const size_t MB = 1024ull * 1024ull;
  __hip_bfloat16* q   = (__hip_bfloat16*)(ws);             // 16 MB (reused as ctx)
  __hip_bfloat16* k   = (__hip_bfloat16*)(ws + 16 * MB);   // 16 MB
  __hip_bfloat16* vT  = (__hip_bfloat16*)(ws + 32 * MB);   // 16 MB, [h*64+d][b*2048+s]
  __hip_bfloat16* woT = (__hip_bfloat16*)(ws + 48 * MB);   // 2 MB -> 50 MB total
  __hip_bfloat16* ctx = q;  // attention reads its Q region before writing it

  // Pre-final scratch inside d_out's 32MB fp32 buffer (stream-ordered reuse):
  char* outc = (char*)d_out;
  __hip_bfloat16* xb    = (__hip_bfloat16*)(outc);            // [0, 16 MB)
  __hip_bfloat16* wcatT = (__hip_bfloat16*)(outc + 16 * MB);  // [16, 22 MB)

  prep_kernel<<<8192 + 4096, 256, 0, stream>>>(
      x, xb, Wq, Wk, Wv, Wo,
      wcatT, wcatT + 1024 * 1024, wcatT + 2048 * 1024, woT);

  gemm_qkv<<<dim3(24, 64), 256, 0, stream>>>(xb, wcatT, q, k, vT);

  attn_kernel<<<1024, 256, 0, stream>>>(q, k, vT, ctx);

  gemm_bt_f32out<<<dim3(8, 64), 256, 0, stream>>>(ctx, woT, out, bo, 8192, 1024, 1024);
}